// Round 1
// baseline (1112.238 us; speedup 1.0000x reference)
//
#include <hip/hip_runtime.h>

#define C 48
#define HH 192
#define WW 192
#define HP 96
#define WP 96
#define NP 9216   // 96*96
#define O 16
#define NS1 8     // n-splits pass1
#define NS2 16    // n-splits pass2

// ws layout (float offsets)
#define OFF_X     0         // x (pooled): [48][9216]
#define OFF_Q     442368    // q: [9216][16]
#define OFF_K     589824    // k: [16][9216]
#define OFF_VT    737280    // vt: [9216][48]
#define OFF_DEN   1179648   // den: [9216]
#define OFF_OT    1188864   // oT: [9216][48]
#define OFF_OUT48 1631232   // out48: [48][9216]
// total floats: 2073600  (8.29 MB)

__global__ void pool_k(const float* __restrict__ in, float* __restrict__ x) {
    int idx = blockIdx.x * 256 + threadIdx.x;
    if (idx >= C * NP) return;
    int c = idx / NP, r = idx % NP;
    int y = r / WP, xx = r % WP;
    const float* p = in + (size_t)c * HH * WW + (2 * y) * WW + 2 * xx;
    x[idx] = 0.25f * (p[0] + p[1] + p[WW] + p[WW + 1]);
}

__global__ void qkv_k(const float* __restrict__ x,
                      const float* __restrict__ qw, const float* __restrict__ qb,
                      const float* __restrict__ kw, const float* __restrict__ kb,
                      const float* __restrict__ vw, const float* __restrict__ vb,
                      float* __restrict__ q, float* __restrict__ k,
                      float* __restrict__ vt) {
    int tid = blockIdx.x * 256 + threadIdx.x;   // 5*9216 threads
    int n = tid % NP;
    int g = tid / NP;   // 0: q, 1: k, 2..4: v chunks
    float f[C];
#pragma unroll
    for (int c = 0; c < C; ++c) f[c] = x[c * NP + n];
    if (g == 0) {
#pragma unroll
        for (int o = 0; o < O; ++o) {
            float a = qb[o];
#pragma unroll
            for (int c = 0; c < C; ++c) a += qw[o * C + c] * f[c];
            q[n * O + o] = a;
        }
    } else if (g == 1) {
#pragma unroll
        for (int o = 0; o < O; ++o) {
            float a = kb[o];
#pragma unroll
            for (int c = 0; c < C; ++c) a += kw[o * C + c] * f[c];
            k[o * NP + n] = a;
        }
    } else {
        int c0 = (g - 2) * 16;
#pragma unroll
        for (int oo = 0; oo < 16; ++oo) {
            int o = c0 + oo;
            float a = vb[o];
#pragma unroll
            for (int c = 0; c < C; ++c) a += vw[o * C + c] * f[c];
            vt[n * C + o] = a;
        }
    }
}

// pass 1: den[m] = sum_n exp(q[n,:] . kcol[m])
__global__ void pass1_k(const float* __restrict__ q, const float* __restrict__ k,
                        float* __restrict__ den) {
    int bm = blockIdx.x % 36;
    int ns = blockIdx.x / 36;
    int m = bm * 256 + threadIdx.x;
    float kc[O];
#pragma unroll
    for (int o = 0; o < O; ++o) kc[o] = k[o * NP + m];
    int n0 = ns * (NP / NS1), n1 = n0 + NP / NS1;
    float acc = 0.f;
    for (int n = n0; n < n1; ++n) {
        const float4* qp = (const float4*)(q + (size_t)n * O);
        float4 q0 = qp[0], q1 = qp[1], q2 = qp[2], q3 = qp[3];
        float s = q0.x * kc[0] + q0.y * kc[1] + q0.z * kc[2] + q0.w * kc[3]
                + q1.x * kc[4] + q1.y * kc[5] + q1.z * kc[6] + q1.w * kc[7]
                + q2.x * kc[8] + q2.y * kc[9] + q2.z * kc[10] + q2.w * kc[11]
                + q3.x * kc[12] + q3.y * kc[13] + q3.z * kc[14] + q3.w * kc[15];
        acc += __expf(s);
    }
    atomicAdd(&den[m], acc);
}

// pass 2: oT[m][c] = sum_n exp(q[n,:] . kcol[m]) * vt[n][c]
__global__ void pass2_k(const float* __restrict__ q, const float* __restrict__ k,
                        const float* __restrict__ vt, float* __restrict__ oT) {
    int bm = blockIdx.x % 36;
    int ns = blockIdx.x / 36;
    int m = bm * 256 + threadIdx.x;
    float kc[O];
#pragma unroll
    for (int o = 0; o < O; ++o) kc[o] = k[o * NP + m];
    float acc[C];
#pragma unroll
    for (int c = 0; c < C; ++c) acc[c] = 0.f;
    int n0 = ns * (NP / NS2), n1 = n0 + NP / NS2;
    for (int n = n0; n < n1; ++n) {
        const float4* qp = (const float4*)(q + (size_t)n * O);
        float4 q0 = qp[0], q1 = qp[1], q2 = qp[2], q3 = qp[3];
        float s = q0.x * kc[0] + q0.y * kc[1] + q0.z * kc[2] + q0.w * kc[3]
                + q1.x * kc[4] + q1.y * kc[5] + q1.z * kc[6] + q1.w * kc[7]
                + q2.x * kc[8] + q2.y * kc[9] + q2.z * kc[10] + q2.w * kc[11]
                + q3.x * kc[12] + q3.y * kc[13] + q3.z * kc[14] + q3.w * kc[15];
        float p = __expf(s);
        const float4* vp = (const float4*)(vt + (size_t)n * C);
#pragma unroll
        for (int j = 0; j < 12; ++j) {
            float4 v4 = vp[j];
            acc[4 * j + 0] += p * v4.x;
            acc[4 * j + 1] += p * v4.y;
            acc[4 * j + 2] += p * v4.z;
            acc[4 * j + 3] += p * v4.w;
        }
    }
#pragma unroll
    for (int c = 0; c < C; ++c) atomicAdd(&oT[(size_t)m * C + c], acc[c]);
}

// out48[c][m] = gamma * oT[m][c] / den[m] + x[c][m]
__global__ void epi_k(const float* __restrict__ oT, const float* __restrict__ den,
                      const float* __restrict__ x, const float* __restrict__ gamma,
                      float* __restrict__ out48) {
    int idx = blockIdx.x * 256 + threadIdx.x;
    if (idx >= C * NP) return;
    int c = idx / NP, m = idx % NP;
    out48[idx] = gamma[0] * (oT[(size_t)m * C + c] / den[m]) + x[idx];
}

// ConvTranspose2d(48->48, k=4, s=2, p=1): y[co,oy,ox] = sum_ci,taps dw[ci,co,ky,kx]*out48[ci,iy,ix] + db[co]
// valid taps: oy = 2*iy + ky - 1  (2 per axis)
__global__ void convt_k(const float* __restrict__ out48, const float* __restrict__ dw,
                        const float* __restrict__ db, float* __restrict__ y) {
    int idx = blockIdx.x * 256 + threadIdx.x;
    if (idx >= C * HH * WW) return;
    int co = idx / (HH * WW);
    int r = idx % (HH * WW);
    int oy = r / WW, ox = r % WW;

    int iy[2], ky[2], ny = 0;
    if ((oy & 1) == 0) {
        int a = oy >> 1;       { iy[ny] = a; ky[ny] = 1; ny++; }
        a = (oy >> 1) - 1;     if (a >= 0) { iy[ny] = a; ky[ny] = 3; ny++; }
    } else {
        int a = (oy + 1) >> 1; if (a < HP) { iy[ny] = a; ky[ny] = 0; ny++; }
        a = (oy - 1) >> 1;     { iy[ny] = a; ky[ny] = 2; ny++; }
    }
    int ix[2], kx[2], nx = 0;
    if ((ox & 1) == 0) {
        int a = ox >> 1;       { ix[nx] = a; kx[nx] = 1; nx++; }
        a = (ox >> 1) - 1;     if (a >= 0) { ix[nx] = a; kx[nx] = 3; nx++; }
    } else {
        int a = (ox + 1) >> 1; if (a < WP) { ix[nx] = a; kx[nx] = 0; nx++; }
        a = (ox - 1) >> 1;     { ix[nx] = a; kx[nx] = 2; nx++; }
    }

    float acc = db[co];
    for (int t = 0; t < ny; ++t) {
        for (int u = 0; u < nx; ++u) {
            const float* wp = dw + ((size_t)co * 4 + ky[t]) * 4 + kx[u]; // + ci*C*16
            const float* ip = out48 + iy[t] * WP + ix[u];                // + ci*NP
            float a = 0.f;
#pragma unroll
            for (int ci = 0; ci < C; ++ci)
                a += wp[(size_t)ci * C * 16] * ip[(size_t)ci * NP];
            acc += a;
        }
    }
    y[idx] = acc;
}

extern "C" void kernel_launch(void* const* d_in, const int* in_sizes, int n_in,
                              void* d_out, int out_size, void* d_ws, size_t ws_size,
                              hipStream_t stream) {
    const float* in    = (const float*)d_in[0];
    const float* qw    = (const float*)d_in[1];
    const float* qb    = (const float*)d_in[2];
    const float* kw    = (const float*)d_in[3];
    const float* kb    = (const float*)d_in[4];
    const float* vw    = (const float*)d_in[5];
    const float* vb    = (const float*)d_in[6];
    const float* gamma = (const float*)d_in[7];
    const float* dw    = (const float*)d_in[8];
    const float* db    = (const float*)d_in[9];
    float* out = (float*)d_out;

    float* ws    = (float*)d_ws;
    float* x     = ws + OFF_X;
    float* q     = ws + OFF_Q;
    float* k     = ws + OFF_K;
    float* vt    = ws + OFF_VT;
    float* den   = ws + OFF_DEN;
    float* oT    = ws + OFF_OT;
    float* out48 = ws + OFF_OUT48;

    pool_k<<<(C * NP + 255) / 256, 256, 0, stream>>>(in, x);
    qkv_k<<<(5 * NP) / 256, 256, 0, stream>>>(x, qw, qb, kw, kb, vw, vb, q, k, vt);
    // zero den + oT (contiguous region) for atomic accumulation
    hipMemsetAsync(den, 0, (size_t)(NP + NP * C) * sizeof(float), stream);
    pass1_k<<<36 * NS1, 256, 0, stream>>>(q, k, den);
    pass2_k<<<36 * NS2, 256, 0, stream>>>(q, k, vt, oT);
    epi_k<<<(C * NP + 255) / 256, 256, 0, stream>>>(oT, den, x, gamma, out48);
    convt_k<<<(C * HH * WW) / 256, 256, 0, stream>>>(out48, dw, db, out);
}

// Round 2
// 287.967 us; speedup vs baseline: 3.8624x; 3.8624x over previous
//
#include <hip/hip_runtime.h>
#include <hip/hip_bf16.h>

#define C 48
#define HH 192
#define WW 192
#define HP 96
#define WP 96
#define NP 9216   // 96*96

// ws layout (float offsets)
#define OFF_X     0         // x (pooled): [48][9216] f32
#define OFF_OUT48 442368    // out48: [48][9216] f32
#define OFF_O     884736    // O: [9216][64] f32 (col 48 = den)
#define OFF_QB    1474560   // QB: [9216][16] bf16 (=q)      (ushort at ws+off)
#define OFF_KB    1548288   // KB: [9216][16] bf16 (=k^T)
#define OFF_VB    1622016   // VB: [64][9216] bf16 (rows 0..47 = v, row 48 = 1.0, 49..63 = 0)
// total floats: 1916928 (7.67 MB)

typedef __attribute__((ext_vector_type(4))) short s16x4;
typedef __attribute__((ext_vector_type(4))) float f32x4;

#if __has_builtin(__builtin_amdgcn_mfma_f32_16x16x16bf16_1k)
static __device__ inline f32x4 mfma16(s16x4 a, s16x4 b, f32x4 c) {
    return __builtin_amdgcn_mfma_f32_16x16x16bf16_1k(a, b, c, 0, 0, 0);
}
#else
static __device__ inline f32x4 mfma16(s16x4 a, s16x4 b, f32x4 c) {
    asm volatile("v_mfma_f32_16x16x16_bf16 %0, %1, %2, %0" : "+v"(c) : "v"(a), "v"(b));
    return c;
}
#endif

static __device__ inline unsigned short f2bf(float f) {
    union { float f; unsigned u; } v; v.f = f;
    unsigned r = v.u + 0x7fff + ((v.u >> 16) & 1);
    return (unsigned short)(r >> 16);
}

static __device__ inline s16x4 pack_bf16x4(float a, float b, float c, float d) {
    __hip_bfloat162 h0 = __float22bfloat162_rn(make_float2(a, b));
    __hip_bfloat162 h1 = __float22bfloat162_rn(make_float2(c, d));
    union { unsigned u[2]; s16x4 v; } pu;
    pu.u[0] = *reinterpret_cast<unsigned*>(&h0);
    pu.u[1] = *reinterpret_cast<unsigned*>(&h1);
    return pu.v;
}

__global__ void pool_k(const float* __restrict__ in, float* __restrict__ x) {
    int idx = blockIdx.x * 256 + threadIdx.x;
    if (idx >= C * NP) return;
    int c = idx / NP, r = idx % NP;
    int y = r / WP, xx = r % WP;
    const float* p = in + (size_t)c * HH * WW + (2 * y) * WW + 2 * xx;
    x[idx] = 0.25f * (p[0] + p[1] + p[WW] + p[WW + 1]);
}

// thread groups: g0 -> QB (q), g1 -> KB (k^T) + VB pad rows, g2..4 -> VB rows
__global__ void qkvprep_k(const float* __restrict__ x,
                          const float* __restrict__ qw, const float* __restrict__ qb,
                          const float* __restrict__ kw, const float* __restrict__ kb,
                          const float* __restrict__ vw, const float* __restrict__ vb,
                          unsigned short* __restrict__ QB, unsigned short* __restrict__ KB,
                          unsigned short* __restrict__ VB) {
    int tid = blockIdx.x * 256 + threadIdx.x;   // 5*9216 threads
    int p = tid % NP;
    int g = tid / NP;
    float f[C];
#pragma unroll
    for (int c = 0; c < C; ++c) f[c] = x[c * NP + p];
    if (g == 0) {
#pragma unroll
        for (int o = 0; o < 16; ++o) {
            float a = qb[o];
#pragma unroll
            for (int c = 0; c < C; ++c) a += qw[o * C + c] * f[c];
            QB[p * 16 + o] = f2bf(a);
        }
    } else if (g == 1) {
#pragma unroll
        for (int o = 0; o < 16; ++o) {
            float a = kb[o];
#pragma unroll
            for (int c = 0; c < C; ++c) a += kw[o * C + c] * f[c];
            KB[p * 16 + o] = f2bf(a);
        }
        VB[(size_t)48 * NP + p] = 0x3F80;  // bf16(1.0) -> den row
#pragma unroll
        for (int r = 49; r < 64; ++r) VB[(size_t)r * NP + p] = 0;
    } else {
        int c0 = (g - 2) * 16;
#pragma unroll
        for (int oo = 0; oo < 16; ++oo) {
            int o = c0 + oo;
            float a = vb[o];
#pragma unroll
            for (int c = 0; c < C; ++c) a += vw[o * C + c] * f[c];
            VB[(size_t)o * NP + p] = f2bf(a);
        }
    }
}

// Fused attention: O[m][c] += sum_n exp(score(m,n)) * V'[n][c]; col 48 accumulates den.
// score(m,n) = sum_d q[n,d] * k[d,m].  Swapped MFMA: T = K'_n x Q'^T gives lane-local P rows.
#define MBLKS 72      // 9216 / 128
#define NSPL  16
#define NSTEP 36      // (9216/NSPL)/16
__global__ __launch_bounds__(256) void attn_k(const unsigned short* __restrict__ QB,
                                              const unsigned short* __restrict__ KB,
                                              const unsigned short* __restrict__ VB,
                                              float* __restrict__ O) {
    const int lane = threadIdx.x & 63;
    const int lo = lane & 15, hi = lane >> 4;
    const int wv = threadIdx.x >> 6;
    const int mblk = blockIdx.x % MBLKS;
    const int nspl = blockIdx.x / MBLKS;
    const int mt0 = mblk * 128 + wv * 32;   // wave owns m-tiles [mt0, mt0+16)

    const s16x4 bq0 = *(const s16x4*)(KB + (size_t)(mt0 + lo) * 16 + 4 * hi);
    const s16x4 bq1 = *(const s16x4*)(KB + (size_t)(mt0 + 16 + lo) * 16 + 4 * hi);

    f32x4 o0[4], o1[4];
#pragma unroll
    for (int i = 0; i < 4; ++i) {
        o0[i] = (f32x4){0.f, 0.f, 0.f, 0.f};
        o1[i] = (f32x4){0.f, 0.f, 0.f, 0.f};
    }

    int n0 = nspl * (NP / NSPL);
    const unsigned short* qp = QB + (size_t)(n0 + lo) * 16 + 4 * hi;
    const unsigned short* vp = VB + (size_t)lo * NP + n0 + 4 * hi;

    for (int s = 0; s < NSTEP; ++s) {
        s16x4 aq = *(const s16x4*)qp;              // K'[n0+lo][4hi+e]
        qp += 16 * 16;
        s16x4 bv0 = *(const s16x4*)(vp);
        s16x4 bv1 = *(const s16x4*)(vp + (size_t)16 * NP);
        s16x4 bv2 = *(const s16x4*)(vp + (size_t)32 * NP);
        s16x4 bv3 = *(const s16x4*)(vp + (size_t)48 * NP);
        vp += 16;

        f32x4 z = {0.f, 0.f, 0.f, 0.f};
        f32x4 t0 = mfma16(aq, bq0, z);   // t0[j] = score(m=mt0+lo,    n=n0+4hi+j)
        f32x4 t1 = mfma16(aq, bq1, z);   // t1[j] = score(m=mt0+16+lo, n=n0+4hi+j)

        s16x4 p0 = pack_bf16x4(__expf(t0[0]), __expf(t0[1]), __expf(t0[2]), __expf(t0[3]));
        s16x4 p1 = pack_bf16x4(__expf(t1[0]), __expf(t1[1]), __expf(t1[2]), __expf(t1[3]));

        o0[0] = mfma16(p0, bv0, o0[0]);
        o0[1] = mfma16(p0, bv1, o0[1]);
        o0[2] = mfma16(p0, bv2, o0[2]);
        o0[3] = mfma16(p0, bv3, o0[3]);
        o1[0] = mfma16(p1, bv0, o1[0]);
        o1[1] = mfma16(p1, bv1, o1[1]);
        o1[2] = mfma16(p1, bv2, o1[2]);
        o1[3] = mfma16(p1, bv3, o1[3]);
    }

#pragma unroll
    for (int ct = 0; ct < 4; ++ct) {
#pragma unroll
        for (int j = 0; j < 4; ++j) {
            atomicAdd(&O[(size_t)(mt0 + 4 * hi + j) * 64 + 16 * ct + lo], o0[ct][j]);
            atomicAdd(&O[(size_t)(mt0 + 16 + 4 * hi + j) * 64 + 16 * ct + lo], o1[ct][j]);
        }
    }
}

// out48[c][m] = gamma * O[m][c] / O[m][48] + x[c][m]
__global__ void epi_k(const float* __restrict__ O, const float* __restrict__ x,
                      const float* __restrict__ gamma, float* __restrict__ out48) {
    int idx = blockIdx.x * 256 + threadIdx.x;
    if (idx >= C * NP) return;
    int c = idx / NP, m = idx % NP;
    out48[idx] = gamma[0] * (O[(size_t)m * 64 + c] / O[(size_t)m * 64 + 48]) + x[idx];
}

// ConvTranspose2d(48->48, k=4, s=2, p=1)
__global__ void convt_k(const float* __restrict__ out48, const float* __restrict__ dw,
                        const float* __restrict__ db, float* __restrict__ y) {
    int idx = blockIdx.x * 256 + threadIdx.x;
    if (idx >= C * HH * WW) return;
    int co = idx / (HH * WW);
    int r = idx % (HH * WW);
    int oy = r / WW, ox = r % WW;

    int iy[2], ky[2], ny = 0;
    if ((oy & 1) == 0) {
        int a = oy >> 1;       { iy[ny] = a; ky[ny] = 1; ny++; }
        a = (oy >> 1) - 1;     if (a >= 0) { iy[ny] = a; ky[ny] = 3; ny++; }
    } else {
        int a = (oy + 1) >> 1; if (a < HP) { iy[ny] = a; ky[ny] = 0; ny++; }
        a = (oy - 1) >> 1;     { iy[ny] = a; ky[ny] = 2; ny++; }
    }
    int ix[2], kx[2], nx = 0;
    if ((ox & 1) == 0) {
        int a = ox >> 1;       { ix[nx] = a; kx[nx] = 1; nx++; }
        a = (ox >> 1) - 1;     if (a >= 0) { ix[nx] = a; kx[nx] = 3; nx++; }
    } else {
        int a = (ox + 1) >> 1; if (a < WP) { ix[nx] = a; kx[nx] = 0; nx++; }
        a = (ox - 1) >> 1;     { ix[nx] = a; kx[nx] = 2; nx++; }
    }

    float acc = db[co];
    for (int t = 0; t < ny; ++t) {
        for (int u = 0; u < nx; ++u) {
            const float* wp = dw + ((size_t)co * 4 + ky[t]) * 4 + kx[u];
            const float* ip = out48 + iy[t] * WP + ix[u];
            float a = 0.f;
#pragma unroll
            for (int ci = 0; ci < C; ++ci)
                a += wp[(size_t)ci * C * 16] * ip[(size_t)ci * NP];
            acc += a;
        }
    }
    y[idx] = acc;
}

extern "C" void kernel_launch(void* const* d_in, const int* in_sizes, int n_in,
                              void* d_out, int out_size, void* d_ws, size_t ws_size,
                              hipStream_t stream) {
    const float* in    = (const float*)d_in[0];
    const float* qw    = (const float*)d_in[1];
    const float* qb    = (const float*)d_in[2];
    const float* kw    = (const float*)d_in[3];
    const float* kb    = (const float*)d_in[4];
    const float* vw    = (const float*)d_in[5];
    const float* vb    = (const float*)d_in[6];
    const float* gamma = (const float*)d_in[7];
    const float* dw    = (const float*)d_in[8];
    const float* db    = (const float*)d_in[9];
    float* out = (float*)d_out;

    float* ws    = (float*)d_ws;
    float* x     = ws + OFF_X;
    float* out48 = ws + OFF_OUT48;
    float* O     = ws + OFF_O;
    unsigned short* QB = (unsigned short*)(ws + OFF_QB);
    unsigned short* KB = (unsigned short*)(ws + OFF_KB);
    unsigned short* VB = (unsigned short*)(ws + OFF_VB);

    pool_k<<<(C * NP + 255) / 256, 256, 0, stream>>>(in, x);
    qkvprep_k<<<(5 * NP) / 256, 256, 0, stream>>>(x, qw, qb, kw, kb, vw, vb, QB, KB, VB);
    hipMemsetAsync(O, 0, (size_t)NP * 64 * sizeof(float), stream);
    attn_k<<<MBLKS * NSPL, 256, 0, stream>>>(QB, KB, VB, O);
    epi_k<<<(C * NP + 255) / 256, 256, 0, stream>>>(O, x, gamma, out48);
    convt_k<<<(C * HH * WW) / 256, 256, 0, stream>>>(out48, dw, db, out);
}

// Round 3
// 159.256 us; speedup vs baseline: 6.9840x; 1.8082x over previous
//
#include <hip/hip_runtime.h>
#include <hip/hip_bf16.h>

#define C 48
#define HH 192
#define WW 192
#define HP 96
#define WP 96
#define NP 9216   // 96*96

// ws layout (float offsets)
#define OFF_X     0         // x (pooled): [48][9216] f32
#define OFF_O     442368    // O: [9216][64] f32 (col 48 = den)
#define OFF_QB    1032192   // QB: [9216][16] bf16
#define OFF_KB    1105920   // KB: [9216][16] bf16
#define OFF_VB    1179648   // VB: [64][9216] bf16 (rows 48=1.0, 49..63=0)
#define OFF_XTP   1474560   // XTP: [98*98][64] bf16, halo+ci-pad zeros
#define OFF_WB    1781888   // WB: [16][48][64] bf16
// total floats: 1806464 (7.23 MB)

typedef __attribute__((ext_vector_type(4))) short s16x4;
typedef __attribute__((ext_vector_type(8))) short s16x8;
typedef __attribute__((ext_vector_type(4))) float f32x4;

#if __has_builtin(__builtin_amdgcn_mfma_f32_16x16x16bf16_1k)
static __device__ inline f32x4 mfma16(s16x4 a, s16x4 b, f32x4 c) {
    return __builtin_amdgcn_mfma_f32_16x16x16bf16_1k(a, b, c, 0, 0, 0);
}
#else
static __device__ inline f32x4 mfma16(s16x4 a, s16x4 b, f32x4 c) {
    asm volatile("v_mfma_f32_16x16x16_bf16 %0, %1, %2, %0" : "+v"(c) : "v"(a), "v"(b));
    return c;
}
#endif

static __device__ inline f32x4 mfma32(s16x8 a, s16x8 b, f32x4 c) {
    return __builtin_amdgcn_mfma_f32_16x16x32_bf16(a, b, c, 0, 0, 0);
}

static __device__ inline unsigned short f2bf(float f) {
    union { float f; unsigned u; } v; v.f = f;
    unsigned r = v.u + 0x7fff + ((v.u >> 16) & 1);
    return (unsigned short)(r >> 16);
}

static __device__ inline s16x4 pack_bf16x4(float a, float b, float c, float d) {
    __hip_bfloat162 h0 = __float22bfloat162_rn(make_float2(a, b));
    __hip_bfloat162 h1 = __float22bfloat162_rn(make_float2(c, d));
    union { unsigned u[2]; s16x4 v; } pu;
    pu.u[0] = *reinterpret_cast<unsigned*>(&h0);
    pu.u[1] = *reinterpret_cast<unsigned*>(&h1);
    return pu.v;
}

__global__ void pool_k(const float* __restrict__ in, float* __restrict__ x) {
    int idx = blockIdx.x * 256 + threadIdx.x;
    if (idx >= C * NP) return;
    int c = idx / NP, r = idx % NP;
    int y = r / WP, xx = r % WP;
    const float* p = in + (size_t)c * HH * WW + (2 * y) * WW + 2 * xx;
    x[idx] = 0.25f * (p[0] + p[1] + p[WW] + p[WW + 1]);
}

__global__ void qkvprep_k(const float* __restrict__ x,
                          const float* __restrict__ qw, const float* __restrict__ qb,
                          const float* __restrict__ kw, const float* __restrict__ kb,
                          const float* __restrict__ vw, const float* __restrict__ vb,
                          unsigned short* __restrict__ QB, unsigned short* __restrict__ KB,
                          unsigned short* __restrict__ VB) {
    int tid = blockIdx.x * 256 + threadIdx.x;   // 5*9216 threads
    int p = tid % NP;
    int g = tid / NP;
    float f[C];
#pragma unroll
    for (int c = 0; c < C; ++c) f[c] = x[c * NP + p];
    if (g == 0) {
#pragma unroll
        for (int o = 0; o < 16; ++o) {
            float a = qb[o];
#pragma unroll
            for (int c = 0; c < C; ++c) a += qw[o * C + c] * f[c];
            QB[p * 16 + o] = f2bf(a);
        }
    } else if (g == 1) {
#pragma unroll
        for (int o = 0; o < 16; ++o) {
            float a = kb[o];
#pragma unroll
            for (int c = 0; c < C; ++c) a += kw[o * C + c] * f[c];
            KB[p * 16 + o] = f2bf(a);
        }
        VB[(size_t)48 * NP + p] = 0x3F80;
#pragma unroll
        for (int r = 49; r < 64; ++r) VB[(size_t)r * NP + p] = 0;
    } else {
        int c0 = (g - 2) * 16;
#pragma unroll
        for (int oo = 0; oo < 16; ++oo) {
            int o = c0 + oo;
            float a = vb[o];
#pragma unroll
            for (int c = 0; c < C; ++c) a += vw[o * C + c] * f[c];
            VB[(size_t)o * NP + p] = f2bf(a);
        }
    }
}

#define MBLKS 72
#define NSPL  16
#define NSTEP 36
__global__ __launch_bounds__(256) void attn_k(const unsigned short* __restrict__ QB,
                                              const unsigned short* __restrict__ KB,
                                              const unsigned short* __restrict__ VB,
                                              float* __restrict__ O) {
    const int lane = threadIdx.x & 63;
    const int lo = lane & 15, hi = lane >> 4;
    const int wv = threadIdx.x >> 6;
    const int mblk = blockIdx.x % MBLKS;
    const int nspl = blockIdx.x / MBLKS;
    const int mt0 = mblk * 128 + wv * 32;

    const s16x4 bq0 = *(const s16x4*)(KB + (size_t)(mt0 + lo) * 16 + 4 * hi);
    const s16x4 bq1 = *(const s16x4*)(KB + (size_t)(mt0 + 16 + lo) * 16 + 4 * hi);

    f32x4 o0[4], o1[4];
#pragma unroll
    for (int i = 0; i < 4; ++i) {
        o0[i] = (f32x4){0.f, 0.f, 0.f, 0.f};
        o1[i] = (f32x4){0.f, 0.f, 0.f, 0.f};
    }

    int n0 = nspl * (NP / NSPL);
    const unsigned short* qp = QB + (size_t)(n0 + lo) * 16 + 4 * hi;
    const unsigned short* vp = VB + (size_t)lo * NP + n0 + 4 * hi;

    for (int s = 0; s < NSTEP; ++s) {
        s16x4 aq = *(const s16x4*)qp;
        qp += 16 * 16;
        s16x4 bv0 = *(const s16x4*)(vp);
        s16x4 bv1 = *(const s16x4*)(vp + (size_t)16 * NP);
        s16x4 bv2 = *(const s16x4*)(vp + (size_t)32 * NP);
        s16x4 bv3 = *(const s16x4*)(vp + (size_t)48 * NP);
        vp += 16;

        f32x4 z = {0.f, 0.f, 0.f, 0.f};
        f32x4 t0 = mfma16(aq, bq0, z);
        f32x4 t1 = mfma16(aq, bq1, z);

        s16x4 p0 = pack_bf16x4(__expf(t0[0]), __expf(t0[1]), __expf(t0[2]), __expf(t0[3]));
        s16x4 p1 = pack_bf16x4(__expf(t1[0]), __expf(t1[1]), __expf(t1[2]), __expf(t1[3]));

        o0[0] = mfma16(p0, bv0, o0[0]);
        o0[1] = mfma16(p0, bv1, o0[1]);
        o0[2] = mfma16(p0, bv2, o0[2]);
        o0[3] = mfma16(p0, bv3, o0[3]);
        o1[0] = mfma16(p1, bv0, o1[0]);
        o1[1] = mfma16(p1, bv1, o1[1]);
        o1[2] = mfma16(p1, bv2, o1[2]);
        o1[3] = mfma16(p1, bv3, o1[3]);
    }

#pragma unroll
    for (int ct = 0; ct < 4; ++ct) {
#pragma unroll
        for (int j = 0; j < 4; ++j) {
            atomicAdd(&O[(size_t)(mt0 + 4 * hi + j) * 64 + 16 * ct + lo], o0[ct][j]);
            atomicAdd(&O[(size_t)(mt0 + 16 + 4 * hi + j) * 64 + 16 * ct + lo], o1[ct][j]);
        }
    }
}

// per m: XTP[(iy+1)*98 + ix+1][c] = bf16( gamma*O[m][c]/den + x[c][m] )
__global__ void epi_k(const float* __restrict__ O, const float* __restrict__ x,
                      const float* __restrict__ gamma, unsigned short* __restrict__ XTP) {
    int m = blockIdx.x * 256 + threadIdx.x;
    if (m >= NP) return;
    int iy = m / WP, ix = m % WP;
    unsigned short* xp = XTP + ((size_t)(iy + 1) * 98 + ix + 1) * 64;
    float den = O[(size_t)m * 64 + 48];
    float rg = gamma[0] / den;
#pragma unroll
    for (int c = 0; c < C; c += 4) {
        f32x4 o4 = *(const f32x4*)(O + (size_t)m * 64 + c);
        ushort4 w;
        w.x = f2bf(rg * o4[0] + x[(size_t)(c + 0) * NP + m]);
        w.y = f2bf(rg * o4[1] + x[(size_t)(c + 1) * NP + m]);
        w.z = f2bf(rg * o4[2] + x[(size_t)(c + 2) * NP + m]);
        w.w = f2bf(rg * o4[3] + x[(size_t)(c + 3) * NP + m]);
        *(ushort4*)(xp + c) = w;
    }
}

// WB[(ky*4+kx)*48+co][ci64] = bf16(dw[ci][co][ky][kx]), ci>=48 -> 0
__global__ void wprep_k(const float* __restrict__ dw, unsigned short* __restrict__ WB) {
    int idx = blockIdx.x * 256 + threadIdx.x;
    if (idx >= 16 * 48 * 64) return;
    int ci = idx & 63;
    int co = (idx >> 6) % 48;
    int kidx = idx / (48 * 64);
    float v = (ci < C) ? dw[((size_t)ci * C + co) * 16 + kidx] : 0.f;
    WB[idx] = f2bf(v);
}

// ConvTranspose2d via MFMA: per (oy', py, px) block, Y[co,pos] = bias + sum_{4 taps} W_tap @ X_shift
__global__ __launch_bounds__(128) void convt_mfma_k(const unsigned short* __restrict__ XTP,
                                                    const unsigned short* __restrict__ WB,
                                                    const float* __restrict__ db,
                                                    float* __restrict__ y) {
    const int lane = threadIdx.x & 63;
    const int lo = lane & 15, hi = lane >> 4;
    const int wv = threadIdx.x >> 6;   // 0..1
    const int b = blockIdx.x;          // 96*2*2
    const int oyp = b >> 2;
    const int py = (b >> 1) & 1;
    const int px = b & 1;

    const int sy[2] = {0, py ? 1 : -1};
    const int kyt[2] = {py ? 2 : 1, py ? 0 : 3};
    const int sx[2] = {0, px ? 1 : -1};
    const int kxt[2] = {px ? 2 : 1, px ? 0 : 3};

    s16x8 bw[2][2][2][3];  // [ty][tx][kk][ct]
#pragma unroll
    for (int ty = 0; ty < 2; ++ty)
#pragma unroll
        for (int tx = 0; tx < 2; ++tx) {
            const unsigned short* wp = WB + (size_t)(kyt[ty] * 4 + kxt[tx]) * 48 * 64;
#pragma unroll
            for (int kk = 0; kk < 2; ++kk)
#pragma unroll
                for (int ct = 0; ct < 3; ++ct)
                    bw[ty][tx][kk][ct] = *(const s16x8*)(wp + (size_t)(ct * 16 + lo) * 64 + kk * 32 + 8 * hi);
        }
    float bias[3];
#pragma unroll
    for (int ct = 0; ct < 3; ++ct) bias[ct] = db[ct * 16 + lo];

    const int oy = 2 * oyp + py;
    for (int i = 0; i < 3; ++i) {
        int ox0 = (wv * 3 + i) * 16;
        f32x4 acc[3];
#pragma unroll
        for (int ct = 0; ct < 3; ++ct) acc[ct] = (f32x4){bias[ct], bias[ct], bias[ct], bias[ct]};
#pragma unroll
        for (int ty = 0; ty < 2; ++ty) {
            int R0 = (oyp + sy[ty] + 1) * 98;
#pragma unroll
            for (int tx = 0; tx < 2; ++tx) {
                const unsigned short* ap = XTP + (size_t)(R0 + ox0 + sx[tx] + 1 + lo) * 64 + 8 * hi;
#pragma unroll
                for (int kk = 0; kk < 2; ++kk) {
                    s16x8 a = *(const s16x8*)(ap + kk * 32);
                    acc[0] = mfma32(a, bw[ty][tx][kk][0], acc[0]);
                    acc[1] = mfma32(a, bw[ty][tx][kk][1], acc[1]);
                    acc[2] = mfma32(a, bw[ty][tx][kk][2], acc[2]);
                }
            }
        }
#pragma unroll
        for (int ct = 0; ct < 3; ++ct)
#pragma unroll
            for (int j = 0; j < 4; ++j)
                y[(size_t)(ct * 16 + lo) * (HH * WW) + oy * WW + 2 * (ox0 + 4 * hi + j) + px] = acc[ct][j];
    }
}

extern "C" void kernel_launch(void* const* d_in, const int* in_sizes, int n_in,
                              void* d_out, int out_size, void* d_ws, size_t ws_size,
                              hipStream_t stream) {
    const float* in    = (const float*)d_in[0];
    const float* qw    = (const float*)d_in[1];
    const float* qb    = (const float*)d_in[2];
    const float* kw    = (const float*)d_in[3];
    const float* kb    = (const float*)d_in[4];
    const float* vw    = (const float*)d_in[5];
    const float* vb    = (const float*)d_in[6];
    const float* gamma = (const float*)d_in[7];
    const float* dw    = (const float*)d_in[8];
    const float* db    = (const float*)d_in[9];
    float* out = (float*)d_out;

    float* ws = (float*)d_ws;
    float* x  = ws + OFF_X;
    float* O  = ws + OFF_O;
    unsigned short* QB  = (unsigned short*)(ws + OFF_QB);
    unsigned short* KB  = (unsigned short*)(ws + OFF_KB);
    unsigned short* VB  = (unsigned short*)(ws + OFF_VB);
    unsigned short* XTP = (unsigned short*)(ws + OFF_XTP);
    unsigned short* WB  = (unsigned short*)(ws + OFF_WB);

    pool_k<<<(C * NP + 255) / 256, 256, 0, stream>>>(in, x);
    qkvprep_k<<<(5 * NP) / 256, 256, 0, stream>>>(x, qw, qb, kw, kb, vw, vb, QB, KB, VB);
    hipMemsetAsync(O, 0, (size_t)NP * 64 * sizeof(float), stream);
    hipMemsetAsync(XTP, 0, (size_t)98 * 98 * 64 * sizeof(unsigned short), stream);
    wprep_k<<<(16 * 48 * 64) / 256, 256, 0, stream>>>(dw, WB);
    attn_k<<<MBLKS * NSPL, 256, 0, stream>>>(QB, KB, VB, O);
    epi_k<<<(NP + 255) / 256, 256, 0, stream>>>(O, x, gamma, XTP);
    convt_mfma_k<<<96 * 2 * 2, 128, 0, stream>>>(XTP, WB, db, out);
}

// Round 4
// 149.628 us; speedup vs baseline: 7.4334x; 1.0643x over previous
//
#include <hip/hip_runtime.h>
#include <hip/hip_bf16.h>

#define C 48
#define HH 192
#define WW 192
#define HP 96
#define WP 96
#define NP 9216   // 96*96

// ws layout (float offsets)
#define OFF_X     0         // x (pooled): [48][9216] f32
#define OFF_O     442368    // O: [9216][64] f32 (col 48 = den)
#define OFF_QB    1032192   // QB: [9216][16] bf16
#define OFF_KB    1105920   // KB: [9216][16] bf16 (pre-scaled by log2e)
#define OFF_VB    1179648   // VB: [64][9216] bf16 (rows 48=1.0, 49..63=0)
#define OFF_XTP   1474560   // XTP: [98*98][64] bf16, halo+ci-pad zeros
#define OFF_WB    1781888   // WB: [16][48][64] bf16
// total floats: 1806464 (7.23 MB)

typedef __attribute__((ext_vector_type(4))) short s16x4;
typedef __attribute__((ext_vector_type(8))) short s16x8;
typedef __attribute__((ext_vector_type(4))) float f32x4;

#if __has_builtin(__builtin_amdgcn_mfma_f32_16x16x16bf16_1k)
static __device__ inline f32x4 mfma16(s16x4 a, s16x4 b, f32x4 c) {
    return __builtin_amdgcn_mfma_f32_16x16x16bf16_1k(a, b, c, 0, 0, 0);
}
#else
static __device__ inline f32x4 mfma16(s16x4 a, s16x4 b, f32x4 c) {
    asm volatile("v_mfma_f32_16x16x16_bf16 %0, %1, %2, %0" : "+v"(c) : "v"(a), "v"(b));
    return c;
}
#endif

static __device__ inline f32x4 mfma32(s16x8 a, s16x8 b, f32x4 c) {
    return __builtin_amdgcn_mfma_f32_16x16x32_bf16(a, b, c, 0, 0, 0);
}

// raw v_exp_f32: computes 2^x (we pre-scale scores by log2e)
static __device__ inline float fexp2(float x) {
    float r;
    asm("v_exp_f32 %0, %1" : "=v"(r) : "v"(x));
    return r;
}

static __device__ inline unsigned short f2bf(float f) {
    union { float f; unsigned u; } v; v.f = f;
    unsigned r = v.u + 0x7fff + ((v.u >> 16) & 1);
    return (unsigned short)(r >> 16);
}

static __device__ inline s16x4 pack_bf16x4(float a, float b, float c, float d) {
    __hip_bfloat162 h0 = __float22bfloat162_rn(make_float2(a, b));
    __hip_bfloat162 h1 = __float22bfloat162_rn(make_float2(c, d));
    union { unsigned u[2]; s16x4 v; } pu;
    pu.u[0] = *reinterpret_cast<unsigned*>(&h0);
    pu.u[1] = *reinterpret_cast<unsigned*>(&h1);
    return pu.v;
}

__global__ void pool_k(const float* __restrict__ in, float* __restrict__ x) {
    int idx = blockIdx.x * 256 + threadIdx.x;
    if (idx >= C * NP) return;
    int c = idx / NP, r = idx % NP;
    int y = r / WP, xx = r % WP;
    const float* p = in + (size_t)c * HH * WW + (2 * y) * WW + 2 * xx;
    x[idx] = 0.25f * (p[0] + p[1] + p[WW] + p[WW + 1]);
}

__global__ void qkvprep_k(const float* __restrict__ x,
                          const float* __restrict__ qw, const float* __restrict__ qb,
                          const float* __restrict__ kw, const float* __restrict__ kb,
                          const float* __restrict__ vw, const float* __restrict__ vb,
                          unsigned short* __restrict__ QB, unsigned short* __restrict__ KB,
                          unsigned short* __restrict__ VB) {
    int tid = blockIdx.x * 256 + threadIdx.x;   // 5*9216 threads
    int p = tid % NP;
    int g = tid / NP;
    float f[C];
#pragma unroll
    for (int c = 0; c < C; ++c) f[c] = x[c * NP + p];
    if (g == 0) {
#pragma unroll
        for (int o = 0; o < 16; ++o) {
            float a = qb[o];
#pragma unroll
            for (int c = 0; c < C; ++c) a += qw[o * C + c] * f[c];
            QB[p * 16 + o] = f2bf(a);
        }
    } else if (g == 1) {
        const float L2E = 1.4426950408889634f;
#pragma unroll
        for (int o = 0; o < 16; ++o) {
            float a = kb[o];
#pragma unroll
            for (int c = 0; c < C; ++c) a += kw[o * C + c] * f[c];
            KB[p * 16 + o] = f2bf(a * L2E);
        }
        VB[(size_t)48 * NP + p] = 0x3F80;
#pragma unroll
        for (int r = 49; r < 64; ++r) VB[(size_t)r * NP + p] = 0;
    } else {
        int c0 = (g - 2) * 16;
#pragma unroll
        for (int oo = 0; oo < 16; ++oo) {
            int o = c0 + oo;
            float a = vb[o];
#pragma unroll
            for (int c = 0; c < C; ++c) a += vw[o * C + c] * f[c];
            VB[(size_t)o * NP + p] = f2bf(a);
        }
    }
}

#define MBLKS 72
#define NSPL  32
#define NSTEP 18   // (NP/NSPL)/16
__global__ __launch_bounds__(256) void attn_k(const unsigned short* __restrict__ QB,
                                              const unsigned short* __restrict__ KB,
                                              const unsigned short* __restrict__ VB,
                                              float* __restrict__ O) {
    const int lane = threadIdx.x & 63;
    const int lo = lane & 15, hi = lane >> 4;
    const int wv = threadIdx.x >> 6;
    const int mblk = blockIdx.x % MBLKS;
    const int nspl = blockIdx.x / MBLKS;
    const int mt0 = mblk * 128 + wv * 32;

    const s16x4 bq0 = *(const s16x4*)(KB + (size_t)(mt0 + lo) * 16 + 4 * hi);
    const s16x4 bq1 = *(const s16x4*)(KB + (size_t)(mt0 + 16 + lo) * 16 + 4 * hi);

    f32x4 o0[4], o1[4];
#pragma unroll
    for (int i = 0; i < 4; ++i) {
        o0[i] = (f32x4){0.f, 0.f, 0.f, 0.f};
        o1[i] = (f32x4){0.f, 0.f, 0.f, 0.f};
    }

    int n0 = nspl * (NP / NSPL);
    const unsigned short* qp = QB + (size_t)(n0 + lo) * 16 + 4 * hi;
    const unsigned short* vp = VB + (size_t)lo * NP + n0 + 4 * hi;

    // pipeline prologue
    s16x4 aq  = *(const s16x4*)qp;
    s16x4 bv0 = *(const s16x4*)(vp);
    s16x4 bv1 = *(const s16x4*)(vp + (size_t)16 * NP);
    s16x4 bv2 = *(const s16x4*)(vp + (size_t)32 * NP);
    s16x4 bv3 = *(const s16x4*)(vp + (size_t)48 * NP);

    for (int s = 0; s < NSTEP; ++s) {
        // prefetch next tile (tail over-read stays inside d_ws; values unused)
        qp += 16 * 16;
        vp += 16;
        s16x4 aqn  = *(const s16x4*)qp;
        s16x4 bvn0 = *(const s16x4*)(vp);
        s16x4 bvn1 = *(const s16x4*)(vp + (size_t)16 * NP);
        s16x4 bvn2 = *(const s16x4*)(vp + (size_t)32 * NP);
        s16x4 bvn3 = *(const s16x4*)(vp + (size_t)48 * NP);

        f32x4 z = {0.f, 0.f, 0.f, 0.f};
        f32x4 t0 = mfma16(aq, bq0, z);
        f32x4 t1 = mfma16(aq, bq1, z);

        s16x4 p0 = pack_bf16x4(fexp2(t0[0]), fexp2(t0[1]), fexp2(t0[2]), fexp2(t0[3]));
        s16x4 p1 = pack_bf16x4(fexp2(t1[0]), fexp2(t1[1]), fexp2(t1[2]), fexp2(t1[3]));

        o0[0] = mfma16(p0, bv0, o0[0]);
        o0[1] = mfma16(p0, bv1, o0[1]);
        o0[2] = mfma16(p0, bv2, o0[2]);
        o0[3] = mfma16(p0, bv3, o0[3]);
        o1[0] = mfma16(p1, bv0, o1[0]);
        o1[1] = mfma16(p1, bv1, o1[1]);
        o1[2] = mfma16(p1, bv2, o1[2]);
        o1[3] = mfma16(p1, bv3, o1[3]);

        aq = aqn; bv0 = bvn0; bv1 = bvn1; bv2 = bvn2; bv3 = bvn3;
    }

#pragma unroll
    for (int ct = 0; ct < 4; ++ct) {
#pragma unroll
        for (int j = 0; j < 4; ++j) {
            atomicAdd(&O[(size_t)(mt0 + 4 * hi + j) * 64 + 16 * ct + lo], o0[ct][j]);
            atomicAdd(&O[(size_t)(mt0 + 16 + 4 * hi + j) * 64 + 16 * ct + lo], o1[ct][j]);
        }
    }
}

// per m: XTP[(iy+1)*98 + ix+1][c] = bf16( gamma*O[m][c]/den + x[c][m] )
__global__ void epi_k(const float* __restrict__ O, const float* __restrict__ x,
                      const float* __restrict__ gamma, unsigned short* __restrict__ XTP) {
    int m = blockIdx.x * 256 + threadIdx.x;
    if (m >= NP) return;
    int iy = m / WP, ix = m % WP;
    unsigned short* xp = XTP + ((size_t)(iy + 1) * 98 + ix + 1) * 64;
    float den = O[(size_t)m * 64 + 48];
    float rg = gamma[0] / den;
#pragma unroll
    for (int c = 0; c < C; c += 4) {
        f32x4 o4 = *(const f32x4*)(O + (size_t)m * 64 + c);
        ushort4 w;
        w.x = f2bf(rg * o4[0] + x[(size_t)(c + 0) * NP + m]);
        w.y = f2bf(rg * o4[1] + x[(size_t)(c + 1) * NP + m]);
        w.z = f2bf(rg * o4[2] + x[(size_t)(c + 2) * NP + m]);
        w.w = f2bf(rg * o4[3] + x[(size_t)(c + 3) * NP + m]);
        *(ushort4*)(xp + c) = w;
    }
}

// WB[(ky*4+kx)*48+co][ci64] = bf16(dw[ci][co][ky][kx]), ci>=48 -> 0
__global__ void wprep_k(const float* __restrict__ dw, unsigned short* __restrict__ WB) {
    int idx = blockIdx.x * 256 + threadIdx.x;
    if (idx >= 16 * 48 * 64) return;
    int ci = idx & 63;
    int co = (idx >> 6) % 48;
    int kidx = idx / (48 * 64);
    float v = (ci < C) ? dw[((size_t)ci * C + co) * 16 + kidx] : 0.f;
    WB[idx] = f2bf(v);
}

// ConvTranspose2d via MFMA
__global__ __launch_bounds__(128) void convt_mfma_k(const unsigned short* __restrict__ XTP,
                                                    const unsigned short* __restrict__ WB,
                                                    const float* __restrict__ db,
                                                    float* __restrict__ y) {
    const int lane = threadIdx.x & 63;
    const int lo = lane & 15, hi = lane >> 4;
    const int wv = threadIdx.x >> 6;   // 0..1
    const int b = blockIdx.x;          // 96*2*2
    const int oyp = b >> 2;
    const int py = (b >> 1) & 1;
    const int px = b & 1;

    const int sy[2] = {0, py ? 1 : -1};
    const int kyt[2] = {py ? 2 : 1, py ? 0 : 3};
    const int sx[2] = {0, px ? 1 : -1};
    const int kxt[2] = {px ? 2 : 1, px ? 0 : 3};

    s16x8 bw[2][2][2][3];  // [ty][tx][kk][ct]
#pragma unroll
    for (int ty = 0; ty < 2; ++ty)
#pragma unroll
        for (int tx = 0; tx < 2; ++tx) {
            const unsigned short* wp = WB + (size_t)(kyt[ty] * 4 + kxt[tx]) * 48 * 64;
#pragma unroll
            for (int kk = 0; kk < 2; ++kk)
#pragma unroll
                for (int ct = 0; ct < 3; ++ct)
                    bw[ty][tx][kk][ct] = *(const s16x8*)(wp + (size_t)(ct * 16 + lo) * 64 + kk * 32 + 8 * hi);
        }
    float bias[3];
#pragma unroll
    for (int ct = 0; ct < 3; ++ct) bias[ct] = db[ct * 16 + lo];

    const int oy = 2 * oyp + py;
    for (int i = 0; i < 3; ++i) {
        int ox0 = (wv * 3 + i) * 16;
        f32x4 acc[3];
#pragma unroll
        for (int ct = 0; ct < 3; ++ct) acc[ct] = (f32x4){bias[ct], bias[ct], bias[ct], bias[ct]};
#pragma unroll
        for (int ty = 0; ty < 2; ++ty) {
            int R0 = (oyp + sy[ty] + 1) * 98;
#pragma unroll
            for (int tx = 0; tx < 2; ++tx) {
                const unsigned short* ap = XTP + (size_t)(R0 + ox0 + sx[tx] + 1 + lo) * 64 + 8 * hi;
#pragma unroll
                for (int kk = 0; kk < 2; ++kk) {
                    s16x8 a = *(const s16x8*)(ap + kk * 32);
                    acc[0] = mfma32(a, bw[ty][tx][kk][0], acc[0]);
                    acc[1] = mfma32(a, bw[ty][tx][kk][1], acc[1]);
                    acc[2] = mfma32(a, bw[ty][tx][kk][2], acc[2]);
                }
            }
        }
#pragma unroll
        for (int ct = 0; ct < 3; ++ct)
#pragma unroll
            for (int j = 0; j < 4; ++j)
                y[(size_t)(ct * 16 + lo) * (HH * WW) + oy * WW + 2 * (ox0 + 4 * hi + j) + px] = acc[ct][j];
    }
}

extern "C" void kernel_launch(void* const* d_in, const int* in_sizes, int n_in,
                              void* d_out, int out_size, void* d_ws, size_t ws_size,
                              hipStream_t stream) {
    const float* in    = (const float*)d_in[0];
    const float* qw    = (const float*)d_in[1];
    const float* qb    = (const float*)d_in[2];
    const float* kw    = (const float*)d_in[3];
    const float* kb    = (const float*)d_in[4];
    const float* vw    = (const float*)d_in[5];
    const float* vb    = (const float*)d_in[6];
    const float* gamma = (const float*)d_in[7];
    const float* dw    = (const float*)d_in[8];
    const float* db    = (const float*)d_in[9];
    float* out = (float*)d_out;

    float* ws = (float*)d_ws;
    float* x  = ws + OFF_X;
    float* O  = ws + OFF_O;
    unsigned short* QB  = (unsigned short*)(ws + OFF_QB);
    unsigned short* KB  = (unsigned short*)(ws + OFF_KB);
    unsigned short* VB  = (unsigned short*)(ws + OFF_VB);
    unsigned short* XTP = (unsigned short*)(ws + OFF_XTP);
    unsigned short* WB  = (unsigned short*)(ws + OFF_WB);

    pool_k<<<(C * NP + 255) / 256, 256, 0, stream>>>(in, x);
    qkvprep_k<<<(5 * NP) / 256, 256, 0, stream>>>(x, qw, qb, kw, kb, vw, vb, QB, KB, VB);
    hipMemsetAsync(O, 0, (size_t)NP * 64 * sizeof(float), stream);
    hipMemsetAsync(XTP, 0, (size_t)98 * 98 * 64 * sizeof(unsigned short), stream);
    wprep_k<<<(16 * 48 * 64) / 256, 256, 0, stream>>>(dw, WB);
    attn_k<<<MBLKS * NSPL, 256, 0, stream>>>(QB, KB, VB, O);
    epi_k<<<(NP + 255) / 256, 256, 0, stream>>>(O, x, gamma, XTP);
    convt_mfma_k<<<96 * 2 * 2, 128, 0, stream>>>(XTP, WB, db, out);
}